// Round 4
// baseline (1722.411 us; speedup 1.0000x reference)
//
#include <hip/hip_runtime.h>
#include <math.h>

// APPNP: h = relu(x@W1+b1)@W2+b2 ; z_{k+1} = 0.9*Ahat z_k + 0.1*h (10 steps); log_softmax
// Ahat = D^-1/2 (A + I) D^-1/2.
// Propagation in u-space: u = D^-1/2 z, so (Ahat z)_i = dinv_i * (sum_{j in N(i)} u_j + u_i)
// -> unweighted gather sum, cols-only CSR (4B/edge), per-node f32 scaling.
// u stored bf16 (gather-BW bound), accumulation f32.

constexpr float ALPHA_ = 0.1f;
constexpr int KSTEPS = 10;

typedef __attribute__((ext_vector_type(8))) short short8;
typedef __attribute__((ext_vector_type(4))) float f32x4;

static __device__ __forceinline__ short f2bf(float f) {
    unsigned u = __builtin_bit_cast(unsigned, f);
    unsigned r = (u + 0x7FFFu + ((u >> 16) & 1u)) >> 16;
    return (short)r;
}
static __device__ __forceinline__ float bf2f(unsigned short b) {
    unsigned u = (unsigned)b << 16;
    return __builtin_bit_cast(float, u);
}

// ---------------- preprocessing ----------------

__global__ void k_init_deg(int* __restrict__ deg, int n) {
    int i = blockIdx.x * 256 + threadIdx.x;
    if (i < n) deg[i] = 1;  // self loop
}

__global__ void k_edge_deg(const int* __restrict__ ei, int* __restrict__ deg, int E) {
    int e = blockIdx.x * 256 + threadIdx.x;
    if (e < E) atomicAdd(&deg[__builtin_nontemporal_load(&ei[e])], 1);
}

__global__ void k_dinv(const int* __restrict__ deg, float* __restrict__ dinv, int n) {
    int i = blockIdx.x * 256 + threadIdx.x;
    if (i < n) dinv[i] = rsqrtf((float)deg[i]);   // deg >= 1 always
}

// block sums of counts (in-degree = deg-1) for prefix scan
__global__ void k_blocksum(const int* __restrict__ deg, int* __restrict__ bsum, int n) {
    __shared__ int lds[4];
    int i = blockIdx.x * 256 + threadIdx.x;
    int c = (i < n) ? deg[i] - 1 : 0;
    for (int o = 32; o; o >>= 1) c += __shfl_xor(c, o, 64);
    int w = threadIdx.x >> 6, lane = threadIdx.x & 63;
    if (lane == 0) lds[w] = c;
    __syncthreads();
    if (threadIdx.x == 0) bsum[blockIdx.x] = lds[0] + lds[1] + lds[2] + lds[3];
}

// exclusive scan of block sums (single block, nb <= 512)
__global__ void k_scan_bsum(const int* __restrict__ bsum, int* __restrict__ boff, int nb) {
    __shared__ int lds[512];
    int t = threadIdx.x;
    int orig = (t < nb) ? bsum[t] : 0;
    int v = orig;
    lds[t] = v;
    __syncthreads();
    for (int o = 1; o < 512; o <<= 1) {
        int add = (t >= o) ? lds[t - o] : 0;
        __syncthreads();
        v += add;
        lds[t] = v;
        __syncthreads();
    }
    if (t < nb) boff[t] = v - orig;
}

// per-block local exclusive scan + offset -> row_ptr, cursor
__global__ void k_scan_write(const int* __restrict__ deg, const int* __restrict__ boff,
                             int* __restrict__ row_ptr, int* __restrict__ cursor, int n) {
    __shared__ int lds[256];
    int i = blockIdx.x * 256 + threadIdx.x;
    int t = threadIdx.x;
    int c = (i < n) ? deg[i] - 1 : 0;
    int v = c;
    lds[t] = v;
    __syncthreads();
    for (int o = 1; o < 256; o <<= 1) {
        int add = (t >= o) ? lds[t - o] : 0;
        __syncthreads();
        v += add;
        lds[t] = v;
        __syncthreads();
    }
    int excl = v - c + boff[blockIdx.x];
    if (i < n) {
        row_ptr[i] = excl;
        cursor[i] = excl;
        if (i == n - 1) row_ptr[n] = excl + c;
    }
}

// cols-only scatter: one 4B store per edge, no dinv gather
__global__ void k_scatter(const int* __restrict__ ei, int* __restrict__ cursor,
                          int* __restrict__ cols, int E) {
    int e = blockIdx.x * 256 + threadIdx.x;
    if (e >= E) return;
    int r = __builtin_nontemporal_load(&ei[e]);
    int c = __builtin_nontemporal_load(&ei[E + e]);
    int pos = atomicAdd(&cursor[r], 1);
    cols[pos] = c;
}

// ---------------- weight packing into MFMA fragment order ----------------
__global__ void k_pack_w1(const float* __restrict__ w1, short* __restrict__ w1f) {
    int t = blockIdx.x * 256 + threadIdx.x;  // 65536 total
    int j = t & 7, lane = (t >> 3) & 63, nb = (t >> 9) & 3, kb = t >> 11;
    int k = kb * 32 + ((lane >> 4) << 3) + j;
    int c = nb * 16 + (lane & 15);
    w1f[t] = f2bf(w1[k * 64 + c]);
}

__global__ void k_pack_w2(const float* __restrict__ w2, short* __restrict__ w2f) {
    int t = blockIdx.x * 256 + threadIdx.x;  // 4096 total
    int j = t & 7, lane = (t >> 3) & 63, nb = (t >> 9) & 3, kb = (t >> 11) & 1;
    int k = kb * 32 + ((lane >> 4) << 3) + j;
    int c = nb * 16 + (lane & 15);
    w2f[t] = f2bf(w2[k * 64 + c]);
}

// ---------------- fused 2-layer MLP via MFMA ----------------
// writes h (f32, teleport term) and u0 = dinv*h (bf16, propagation state)
__launch_bounds__(256)
__global__ void k_mlp(const float* __restrict__ x, const short8* __restrict__ w1f,
                      const float* __restrict__ b1, const short8* __restrict__ w2f,
                      const float* __restrict__ b2, const float* __restrict__ dinv,
                      float* __restrict__ h, unsigned short* __restrict__ u0,
                      int M, int F) {
    __shared__ __align__(16) short c1s[4][16][64];
    int tid = threadIdx.x;
    int w = tid >> 6, lane = tid & 63;
    int hi = lane >> 4, lx = lane & 15;
    int rbase = blockIdx.x * 64 + w * 16;
    int row = rbase + lx;
    size_t rowc = (row < M) ? (size_t)row : (size_t)(M - 1);
    const float* xr = x + rowc * (size_t)F + hi * 8;

    f32x4 acc[4];
#pragma unroll
    for (int nb = 0; nb < 4; ++nb) acc[nb] = (f32x4){0.f, 0.f, 0.f, 0.f};

    int KK = F >> 5;
#pragma unroll 2
    for (int kk = 0; kk < KK; ++kk) {
        float4 a0 = *reinterpret_cast<const float4*>(xr + kk * 32);
        float4 a1 = *reinterpret_cast<const float4*>(xr + kk * 32 + 4);
        short8 af;
        af[0] = f2bf(a0.x); af[1] = f2bf(a0.y); af[2] = f2bf(a0.z); af[3] = f2bf(a0.w);
        af[4] = f2bf(a1.x); af[5] = f2bf(a1.y); af[6] = f2bf(a1.z); af[7] = f2bf(a1.w);
#pragma unroll
        for (int nb = 0; nb < 4; ++nb) {
            short8 bf = w1f[(kk * 4 + nb) * 64 + lane];
            acc[nb] = __builtin_amdgcn_mfma_f32_16x16x32_bf16(af, bf, acc[nb], 0, 0, 0);
        }
    }

    short* my = &c1s[w][0][0];
#pragma unroll
    for (int nb = 0; nb < 4; ++nb) {
        int col = nb * 16 + lx;
        float bb = b1[col];
#pragma unroll
        for (int r = 0; r < 4; ++r) {
            int rr = hi * 4 + r;
            my[rr * 64 + col] = f2bf(fmaxf(acc[nb][r] + bb, 0.f));
        }
    }
    __syncthreads();

    f32x4 acc2[4];
#pragma unroll
    for (int nb = 0; nb < 4; ++nb) acc2[nb] = (f32x4){0.f, 0.f, 0.f, 0.f};
#pragma unroll
    for (int kb = 0; kb < 2; ++kb) {
        short8 af2 = *reinterpret_cast<const short8*>(&my[lx * 64 + kb * 32 + hi * 8]);
#pragma unroll
        for (int nb = 0; nb < 4; ++nb) {
            short8 bf2 = w2f[(kb * 4 + nb) * 64 + lane];
            acc2[nb] = __builtin_amdgcn_mfma_f32_16x16x32_bf16(af2, bf2, acc2[nb], 0, 0, 0);
        }
    }

#pragma unroll
    for (int r = 0; r < 4; ++r) {
        int orow = rbase + hi * 4 + r;
        float dv = (orow < M) ? dinv[orow] : 0.f;
#pragma unroll
        for (int nb = 0; nb < 4; ++nb) {
            int col = nb * 16 + lx;
            if (orow < M) {
                float v = acc2[nb][r] + b2[col];
                h[(size_t)orow * 64 + col] = v;
                u0[(size_t)orow * 64 + col] = (unsigned short)f2bf(dv * v);
            }
        }
    }
}

// ---------------- propagation (pull over cols-only CSR, bf16 u-state) ----------------
__global__ void k_prop(const unsigned short* __restrict__ uin, const float* __restrict__ h,
                       const float* __restrict__ dinv, const int* __restrict__ row_ptr,
                       const int* __restrict__ cols, unsigned short* __restrict__ uout, int n) {
    int wid = threadIdx.x >> 6;
    int lane = threadIdx.x & 63;
    int i = blockIdx.x * 4 + wid;
    if (i >= n) return;
    float di = dinv[i];
    size_t i64 = (size_t)i * 64;
    float ui = bf2f(uin[i64 + lane]);
    int e = row_ptr[i], end = row_ptr[i + 1];
    float a0 = 0.f, a1 = 0.f, a2 = 0.f, a3 = 0.f, a4 = 0.f, a5 = 0.f, a6 = 0.f, a7 = 0.f;
    for (; e + 8 <= end; e += 8) {
        int c0 = __builtin_nontemporal_load(&cols[e]);
        int c1 = __builtin_nontemporal_load(&cols[e + 1]);
        int c2 = __builtin_nontemporal_load(&cols[e + 2]);
        int c3 = __builtin_nontemporal_load(&cols[e + 3]);
        int c4 = __builtin_nontemporal_load(&cols[e + 4]);
        int c5 = __builtin_nontemporal_load(&cols[e + 5]);
        int c6 = __builtin_nontemporal_load(&cols[e + 6]);
        int c7 = __builtin_nontemporal_load(&cols[e + 7]);
        float z0 = bf2f(uin[(size_t)c0 * 64 + lane]);
        float z1 = bf2f(uin[(size_t)c1 * 64 + lane]);
        float z2 = bf2f(uin[(size_t)c2 * 64 + lane]);
        float z3 = bf2f(uin[(size_t)c3 * 64 + lane]);
        float z4 = bf2f(uin[(size_t)c4 * 64 + lane]);
        float z5 = bf2f(uin[(size_t)c5 * 64 + lane]);
        float z6 = bf2f(uin[(size_t)c6 * 64 + lane]);
        float z7 = bf2f(uin[(size_t)c7 * 64 + lane]);
        a0 += z0; a1 += z1; a2 += z2; a3 += z3;
        a4 += z4; a5 += z5; a6 += z6; a7 += z7;
    }
    for (; e < end; ++e) {
        int c = __builtin_nontemporal_load(&cols[e]);
        a0 += bf2f(uin[(size_t)c * 64 + lane]);
    }
    float s = ((a0 + a1) + (a2 + a3)) + ((a4 + a5) + (a6 + a7)) + ui;
    float hz = __builtin_nontemporal_load(&h[i64 + lane]);
    float z = fmaf(0.9f * di, s, ALPHA_ * hz);
    uout[i64 + lane] = (unsigned short)f2bf(di * z);
}

// final step fused with log_softmax, writes f32 out
__global__ void k_prop_lsm(const unsigned short* __restrict__ uin, const float* __restrict__ h,
                           const float* __restrict__ dinv, const int* __restrict__ row_ptr,
                           const int* __restrict__ cols, float* __restrict__ out, int n) {
    int wid = threadIdx.x >> 6;
    int lane = threadIdx.x & 63;
    int i = blockIdx.x * 4 + wid;
    if (i >= n) return;
    float di = dinv[i];
    size_t i64 = (size_t)i * 64;
    float ui = bf2f(uin[i64 + lane]);
    int e = row_ptr[i], end = row_ptr[i + 1];
    float a0 = 0.f, a1 = 0.f, a2 = 0.f, a3 = 0.f, a4 = 0.f, a5 = 0.f, a6 = 0.f, a7 = 0.f;
    for (; e + 8 <= end; e += 8) {
        int c0 = __builtin_nontemporal_load(&cols[e]);
        int c1 = __builtin_nontemporal_load(&cols[e + 1]);
        int c2 = __builtin_nontemporal_load(&cols[e + 2]);
        int c3 = __builtin_nontemporal_load(&cols[e + 3]);
        int c4 = __builtin_nontemporal_load(&cols[e + 4]);
        int c5 = __builtin_nontemporal_load(&cols[e + 5]);
        int c6 = __builtin_nontemporal_load(&cols[e + 6]);
        int c7 = __builtin_nontemporal_load(&cols[e + 7]);
        float z0 = bf2f(uin[(size_t)c0 * 64 + lane]);
        float z1 = bf2f(uin[(size_t)c1 * 64 + lane]);
        float z2 = bf2f(uin[(size_t)c2 * 64 + lane]);
        float z3 = bf2f(uin[(size_t)c3 * 64 + lane]);
        float z4 = bf2f(uin[(size_t)c4 * 64 + lane]);
        float z5 = bf2f(uin[(size_t)c5 * 64 + lane]);
        float z6 = bf2f(uin[(size_t)c6 * 64 + lane]);
        float z7 = bf2f(uin[(size_t)c7 * 64 + lane]);
        a0 += z0; a1 += z1; a2 += z2; a3 += z3;
        a4 += z4; a5 += z5; a6 += z6; a7 += z7;
    }
    for (; e < end; ++e) {
        int c = __builtin_nontemporal_load(&cols[e]);
        a0 += bf2f(uin[(size_t)c * 64 + lane]);
    }
    float s = ((a0 + a1) + (a2 + a3)) + ((a4 + a5) + (a6 + a7)) + ui;
    float hz = __builtin_nontemporal_load(&h[i64 + lane]);
    float acc = fmaf(0.9f * di, s, ALPHA_ * hz);
    float m = acc;
    for (int o = 32; o; o >>= 1) m = fmaxf(m, __shfl_xor(m, o, 64));
    float pp = expf(acc - m);
    float ss = pp;
    for (int o = 32; o; o >>= 1) ss += __shfl_xor(ss, o, 64);
    out[i64 + lane] = (acc - m) - logf(ss);
}

// ---------------- launch ----------------
extern "C" void kernel_launch(void* const* d_in, const int* in_sizes, int n_in,
                              void* d_out, int out_size, void* d_ws, size_t ws_size,
                              hipStream_t stream) {
    const float* x  = (const float*)d_in[0];
    const float* w1 = (const float*)d_in[1];
    const float* b1 = (const float*)d_in[2];
    const float* w2 = (const float*)d_in[3];
    const float* b2 = (const float*)d_in[4];
    const int*   ei = (const int*)d_in[5];
    // d_in[6] = K (always 10; launch count must be graph-static)

    int F = in_sizes[1] / 64;         // 1024
    int N = in_sizes[0] / F;          // 100000
    int E = in_sizes[5] / 2;          // 3200000

    char* p = (char*)d_ws;
    auto alloc = [&](size_t bytes) {
        void* r = (void*)p;
        p += (bytes + 255) & ~(size_t)255;
        return r;
    };
    float*          h    = (float*)alloc((size_t)N * 64 * 4);
    unsigned short* u0   = (unsigned short*)alloc((size_t)N * 64 * 2);
    unsigned short* uA   = (unsigned short*)alloc((size_t)N * 64 * 2);
    unsigned short* uB   = (unsigned short*)alloc((size_t)N * 64 * 2);
    int*   deg     = (int*)alloc((size_t)N * 4);
    float* dinv    = (float*)alloc((size_t)N * 4);
    int*   row_ptr = (int*)alloc((size_t)(N + 1) * 4);
    int*   cursor  = (int*)alloc((size_t)N * 4);
    int*   bsum    = (int*)alloc(4096);
    int*   boff    = (int*)alloc(4096);
    int*   cols    = (int*)alloc((size_t)E * 4);
    short* w1f     = (short*)alloc((size_t)F * 64 * 2);
    short* w2f     = (short*)alloc((size_t)64 * 64 * 2);

    int nb  = (N + 255) / 256;
    int neb = (E + 255) / 256;

    k_init_deg<<<nb, 256, 0, stream>>>(deg, N);
    k_edge_deg<<<neb, 256, 0, stream>>>(ei, deg, E);
    k_dinv<<<nb, 256, 0, stream>>>(deg, dinv, N);
    k_blocksum<<<nb, 256, 0, stream>>>(deg, bsum, N);
    k_scan_bsum<<<1, 512, 0, stream>>>(bsum, boff, nb);
    k_scan_write<<<nb, 256, 0, stream>>>(deg, boff, row_ptr, cursor, N);
    k_scatter<<<neb, 256, 0, stream>>>(ei, cursor, cols, E);
    k_pack_w1<<<(F * 64) / 256, 256, 0, stream>>>(w1, w1f);
    k_pack_w2<<<16, 256, 0, stream>>>(w2, w2f);
    k_mlp<<<(N + 63) / 64, 256, 0, stream>>>(x, (const short8*)w1f, b1,
                                             (const short8*)w2f, b2, dinv, h, u0, N, F);

    const unsigned short* uin = u0;
    unsigned short* bufs[2] = {uA, uB};
    for (int k = 0; k < KSTEPS - 1; ++k) {
        unsigned short* uo = bufs[k & 1];
        k_prop<<<(N + 3) / 4, 256, 0, stream>>>(uin, h, dinv, row_ptr, cols, uo, N);
        uin = uo;
    }
    k_prop_lsm<<<(N + 3) / 4, 256, 0, stream>>>(uin, h, dinv, row_ptr, cols, (float*)d_out, N);
}

// Round 5
// 1133.979 us; speedup vs baseline: 1.5189x; 1.5189x over previous
//
#include <hip/hip_runtime.h>
#include <math.h>

// APPNP: h = relu(x@W1+b1)@W2+b2 ; z_{k+1} = 0.9*Ahat z_k + 0.1*h (10 steps); log_softmax
// Ahat = D^-1/2 (A + I) D^-1/2.
// u-space propagation: u = D^-1/2 z -> (Ahat z)_i = dinv_i * (sum_{j in N(i)} u_j + u_i).
// CSR built by bucketed counting sort (no random-line scatter, no global atomic deg pass).
// u, ah=0.1*h stored bf16; accumulation f32.

constexpr int KSTEPS = 10;

typedef __attribute__((ext_vector_type(8))) short short8;
typedef __attribute__((ext_vector_type(4))) float f32x4;

static __device__ __forceinline__ short f2bf(float f) {
    unsigned u = __builtin_bit_cast(unsigned, f);
    unsigned r = (u + 0x7FFFu + ((u >> 16) & 1u)) >> 16;
    return (short)r;
}
static __device__ __forceinline__ float bf2f(unsigned short b) {
    unsigned u = (unsigned)b << 16;
    return __builtin_bit_cast(float, u);
}

// ---------------- bucketed CSR build ----------------
// bucket = row >> 8 (256 rows per bucket); NB = ceil(N/256) buckets

__global__ void k_zero(int* __restrict__ p, int n) {
    int i = blockIdx.x * 256 + threadIdx.x;
    if (i < n) p[i] = 0;
}

// per-bucket edge counts (rows half of edge_index only)
__global__ void k_hist(const int* __restrict__ ei, int* __restrict__ btot, int E, int NB) {
    __shared__ int hist[512];
    for (int t = threadIdx.x; t < NB; t += 256) hist[t] = 0;
    __syncthreads();
    int base = blockIdx.x * 4096;
#pragma unroll
    for (int k = 0; k < 16; ++k) {
        int e = base + k * 256 + threadIdx.x;
        if (e < E) atomicAdd(&hist[ei[e] >> 8], 1);
    }
    __syncthreads();
    for (int t = threadIdx.x; t < NB; t += 256) {
        int c = hist[t];
        if (c) atomicAdd(&btot[t], c);
    }
}

// exclusive scan of bucket totals (NB <= 512); also bcur init and row_ptr[N]
__global__ void k_scanb(const int* __restrict__ btot, int* __restrict__ bstart,
                        int* __restrict__ bcur, int* __restrict__ row_ptr,
                        int NB, int N, int E) {
    __shared__ int lds[512];
    int t = threadIdx.x;
    int v0 = (t < NB) ? btot[t] : 0;
    int v = v0;
    lds[t] = v;
    __syncthreads();
    for (int o = 1; o < 512; o <<= 1) {
        int a = (t >= o) ? lds[t - o] : 0;
        __syncthreads();
        v += a;
        lds[t] = v;
        __syncthreads();
    }
    if (t < NB) {
        int ex = v - v0;
        bstart[t] = ex;
        bcur[t] = ex;
    }
    if (t == 0) {
        bstart[NB] = E;
        row_ptr[N] = E;
    }
}

// partition edges into bucket slices (dense-run writes)
__launch_bounds__(256)
__global__ void k_part(const int* __restrict__ ei, int* __restrict__ bcur,
                       int2* __restrict__ ebuf, int E, int NB) {
    __shared__ int hist[512], rebase[512], lcur[512];
    for (int t = threadIdx.x; t < NB; t += 256) { hist[t] = 0; lcur[t] = 0; }
    __syncthreads();
    int base = blockIdx.x * 4096;
    int r[16], c[16];
#pragma unroll
    for (int k = 0; k < 16; ++k) {
        int e = base + k * 256 + threadIdx.x;
        bool ok = e < E;
        r[k] = ok ? ei[e] : -1;
        c[k] = ok ? ei[E + e] : 0;
        if (ok) atomicAdd(&hist[r[k] >> 8], 1);
    }
    __syncthreads();
    for (int t = threadIdx.x; t < NB; t += 256) {
        int cnt = hist[t];
        rebase[t] = cnt ? atomicAdd(&bcur[t], cnt) : 0;
    }
    __syncthreads();
#pragma unroll
    for (int k = 0; k < 16; ++k) {
        if (r[k] >= 0) {
            int b = r[k] >> 8;
            int pos = rebase[b] + atomicAdd(&lcur[b], 1);
            ebuf[pos] = make_int2(r[k], c[k]);
        }
    }
}

// per-bucket: row hist -> scan -> row_ptr/dinv, then cols scatter (L2-hot slice)
__launch_bounds__(256)
__global__ void k_bucket(const int2* __restrict__ ebuf, const int* __restrict__ bstart,
                         int* __restrict__ row_ptr, float* __restrict__ dinv,
                         int* __restrict__ cols, int N) {
    __shared__ int cnt[256], cur[256], lds[256];
    int b = blockIdx.x, t = threadIdx.x;
    int s = bstart[b], e2 = bstart[b + 1];
    cnt[t] = 0;
    __syncthreads();
    for (int i = s + t; i < e2; i += 256) {
        int2 p = ebuf[i];
        atomicAdd(&cnt[p.x & 255], 1);
    }
    __syncthreads();
    int v0 = cnt[t];
    int v = v0;
    lds[t] = v;
    __syncthreads();
    for (int o = 1; o < 256; o <<= 1) {
        int a = (t >= o) ? lds[t - o] : 0;
        __syncthreads();
        v += a;
        lds[t] = v;
        __syncthreads();
    }
    int excl = v - v0;
    int row = (b << 8) + t;
    if (row < N) {
        row_ptr[row] = s + excl;
        dinv[row] = rsqrtf((float)(v0 + 1));
    }
    cur[t] = s + excl;
    __syncthreads();
    for (int i = s + t; i < e2; i += 256) {
        int2 p = ebuf[i];
        int pos = atomicAdd(&cur[p.x & 255], 1);
        cols[pos] = p.y;
    }
}

// ---------------- weight packing into MFMA fragment order ----------------
__global__ void k_pack_w1(const float* __restrict__ w1, short* __restrict__ w1f) {
    int t = blockIdx.x * 256 + threadIdx.x;  // 65536 total
    int j = t & 7, lane = (t >> 3) & 63, nb = (t >> 9) & 3, kb = t >> 11;
    int k = kb * 32 + ((lane >> 4) << 3) + j;
    int c = nb * 16 + (lane & 15);
    w1f[t] = f2bf(w1[k * 64 + c]);
}

__global__ void k_pack_w2(const float* __restrict__ w2, short* __restrict__ w2f) {
    int t = blockIdx.x * 256 + threadIdx.x;  // 4096 total
    int j = t & 7, lane = (t >> 3) & 63, nb = (t >> 9) & 3, kb = (t >> 11) & 1;
    int k = kb * 32 + ((lane >> 4) << 3) + j;
    int c = nb * 16 + (lane & 15);
    w2f[t] = f2bf(w2[k * 64 + c]);
}

// ---------------- fused 2-layer MLP via MFMA ----------------
// writes ah = bf16(0.1*h) (teleport term) and u0 = bf16(dinv*h) (propagation state)
__launch_bounds__(256)
__global__ void k_mlp(const float* __restrict__ x, const short8* __restrict__ w1f,
                      const float* __restrict__ b1, const short8* __restrict__ w2f,
                      const float* __restrict__ b2, const float* __restrict__ dinv,
                      unsigned short* __restrict__ ah, unsigned short* __restrict__ u0,
                      int M, int F) {
    __shared__ __align__(16) short c1s[4][16][64];
    int tid = threadIdx.x;
    int w = tid >> 6, lane = tid & 63;
    int hi = lane >> 4, lx = lane & 15;
    int rbase = blockIdx.x * 64 + w * 16;
    int row = rbase + lx;
    size_t rowc = (row < M) ? (size_t)row : (size_t)(M - 1);
    const float* xr = x + rowc * (size_t)F + hi * 8;

    f32x4 acc[4];
#pragma unroll
    for (int nb = 0; nb < 4; ++nb) acc[nb] = (f32x4){0.f, 0.f, 0.f, 0.f};

    int KK = F >> 5;
#pragma unroll 2
    for (int kk = 0; kk < KK; ++kk) {
        float4 a0 = *reinterpret_cast<const float4*>(xr + kk * 32);
        float4 a1 = *reinterpret_cast<const float4*>(xr + kk * 32 + 4);
        short8 af;
        af[0] = f2bf(a0.x); af[1] = f2bf(a0.y); af[2] = f2bf(a0.z); af[3] = f2bf(a0.w);
        af[4] = f2bf(a1.x); af[5] = f2bf(a1.y); af[6] = f2bf(a1.z); af[7] = f2bf(a1.w);
#pragma unroll
        for (int nb = 0; nb < 4; ++nb) {
            short8 bf = w1f[(kk * 4 + nb) * 64 + lane];
            acc[nb] = __builtin_amdgcn_mfma_f32_16x16x32_bf16(af, bf, acc[nb], 0, 0, 0);
        }
    }

    short* my = &c1s[w][0][0];
#pragma unroll
    for (int nb = 0; nb < 4; ++nb) {
        int col = nb * 16 + lx;
        float bb = b1[col];
#pragma unroll
        for (int r = 0; r < 4; ++r) {
            int rr = hi * 4 + r;
            my[rr * 64 + col] = f2bf(fmaxf(acc[nb][r] + bb, 0.f));
        }
    }
    __syncthreads();

    f32x4 acc2[4];
#pragma unroll
    for (int nb = 0; nb < 4; ++nb) acc2[nb] = (f32x4){0.f, 0.f, 0.f, 0.f};
#pragma unroll
    for (int kb = 0; kb < 2; ++kb) {
        short8 af2 = *reinterpret_cast<const short8*>(&my[lx * 64 + kb * 32 + hi * 8]);
#pragma unroll
        for (int nb = 0; nb < 4; ++nb) {
            short8 bf2 = w2f[(kb * 4 + nb) * 64 + lane];
            acc2[nb] = __builtin_amdgcn_mfma_f32_16x16x32_bf16(af2, bf2, acc2[nb], 0, 0, 0);
        }
    }

#pragma unroll
    for (int r = 0; r < 4; ++r) {
        int orow = rbase + hi * 4 + r;
        float dv = (orow < M) ? dinv[orow] : 0.f;
#pragma unroll
        for (int nb = 0; nb < 4; ++nb) {
            int col = nb * 16 + lx;
            if (orow < M) {
                float v = acc2[nb][r] + b2[col];
                ah[(size_t)orow * 64 + col] = (unsigned short)f2bf(0.1f * v);
                u0[(size_t)orow * 64 + col] = (unsigned short)f2bf(dv * v);
            }
        }
    }
}

// ---------------- propagation (pull over cols-only CSR, bf16 u-state) ----------------
__global__ void k_prop(const unsigned short* __restrict__ uin, const unsigned short* __restrict__ ah,
                       const float* __restrict__ dinv, const int* __restrict__ row_ptr,
                       const int* __restrict__ cols, unsigned short* __restrict__ uout, int n) {
    int wid = threadIdx.x >> 6;
    int lane = threadIdx.x & 63;
    int i = blockIdx.x * 4 + wid;
    if (i >= n) return;
    float di = dinv[i];
    size_t i64 = (size_t)i * 64;
    float ui = bf2f(uin[i64 + lane]);
    int e = row_ptr[i], end = row_ptr[i + 1];
    float a0 = 0.f, a1 = 0.f, a2 = 0.f, a3 = 0.f, a4 = 0.f, a5 = 0.f, a6 = 0.f, a7 = 0.f;
    for (; e + 8 <= end; e += 8) {
        int c0 = cols[e],     c1 = cols[e + 1], c2 = cols[e + 2], c3 = cols[e + 3];
        int c4 = cols[e + 4], c5 = cols[e + 5], c6 = cols[e + 6], c7 = cols[e + 7];
        float z0 = bf2f(uin[(size_t)c0 * 64 + lane]);
        float z1 = bf2f(uin[(size_t)c1 * 64 + lane]);
        float z2 = bf2f(uin[(size_t)c2 * 64 + lane]);
        float z3 = bf2f(uin[(size_t)c3 * 64 + lane]);
        float z4 = bf2f(uin[(size_t)c4 * 64 + lane]);
        float z5 = bf2f(uin[(size_t)c5 * 64 + lane]);
        float z6 = bf2f(uin[(size_t)c6 * 64 + lane]);
        float z7 = bf2f(uin[(size_t)c7 * 64 + lane]);
        a0 += z0; a1 += z1; a2 += z2; a3 += z3;
        a4 += z4; a5 += z5; a6 += z6; a7 += z7;
    }
    for (; e < end; ++e) a0 += bf2f(uin[(size_t)cols[e] * 64 + lane]);
    float s = ((a0 + a1) + (a2 + a3)) + ((a4 + a5) + (a6 + a7)) + ui;
    float z = fmaf(0.9f * di, s, bf2f(ah[i64 + lane]));
    uout[i64 + lane] = (unsigned short)f2bf(di * z);
}

// final step fused with log_softmax, writes f32 out
__global__ void k_prop_lsm(const unsigned short* __restrict__ uin, const unsigned short* __restrict__ ah,
                           const float* __restrict__ dinv, const int* __restrict__ row_ptr,
                           const int* __restrict__ cols, float* __restrict__ out, int n) {
    int wid = threadIdx.x >> 6;
    int lane = threadIdx.x & 63;
    int i = blockIdx.x * 4 + wid;
    if (i >= n) return;
    float di = dinv[i];
    size_t i64 = (size_t)i * 64;
    float ui = bf2f(uin[i64 + lane]);
    int e = row_ptr[i], end = row_ptr[i + 1];
    float a0 = 0.f, a1 = 0.f, a2 = 0.f, a3 = 0.f, a4 = 0.f, a5 = 0.f, a6 = 0.f, a7 = 0.f;
    for (; e + 8 <= end; e += 8) {
        int c0 = cols[e],     c1 = cols[e + 1], c2 = cols[e + 2], c3 = cols[e + 3];
        int c4 = cols[e + 4], c5 = cols[e + 5], c6 = cols[e + 6], c7 = cols[e + 7];
        float z0 = bf2f(uin[(size_t)c0 * 64 + lane]);
        float z1 = bf2f(uin[(size_t)c1 * 64 + lane]);
        float z2 = bf2f(uin[(size_t)c2 * 64 + lane]);
        float z3 = bf2f(uin[(size_t)c3 * 64 + lane]);
        float z4 = bf2f(uin[(size_t)c4 * 64 + lane]);
        float z5 = bf2f(uin[(size_t)c5 * 64 + lane]);
        float z6 = bf2f(uin[(size_t)c6 * 64 + lane]);
        float z7 = bf2f(uin[(size_t)c7 * 64 + lane]);
        a0 += z0; a1 += z1; a2 += z2; a3 += z3;
        a4 += z4; a5 += z5; a6 += z6; a7 += z7;
    }
    for (; e < end; ++e) a0 += bf2f(uin[(size_t)cols[e] * 64 + lane]);
    float s = ((a0 + a1) + (a2 + a3)) + ((a4 + a5) + (a6 + a7)) + ui;
    float acc = fmaf(0.9f * di, s, bf2f(ah[i64 + lane]));
    float m = acc;
    for (int o = 32; o; o >>= 1) m = fmaxf(m, __shfl_xor(m, o, 64));
    float pp = expf(acc - m);
    float ss = pp;
    for (int o = 32; o; o >>= 1) ss += __shfl_xor(ss, o, 64);
    out[i64 + lane] = (acc - m) - logf(ss);
}

// ---------------- launch ----------------
extern "C" void kernel_launch(void* const* d_in, const int* in_sizes, int n_in,
                              void* d_out, int out_size, void* d_ws, size_t ws_size,
                              hipStream_t stream) {
    const float* x  = (const float*)d_in[0];
    const float* w1 = (const float*)d_in[1];
    const float* b1 = (const float*)d_in[2];
    const float* w2 = (const float*)d_in[3];
    const float* b2 = (const float*)d_in[4];
    const int*   ei = (const int*)d_in[5];
    // d_in[6] = K (always 10; launch count must be graph-static)

    int F = in_sizes[1] / 64;         // 1024
    int N = in_sizes[0] / F;          // 100000
    int E = in_sizes[5] / 2;          // 3200000
    int NB = (N + 255) >> 8;          // 391 buckets

    char* p = (char*)d_ws;
    auto alloc = [&](size_t bytes) {
        void* r = (void*)p;
        p += (bytes + 255) & ~(size_t)255;
        return r;
    };
    unsigned short* ah   = (unsigned short*)alloc((size_t)N * 64 * 2);
    unsigned short* u0   = (unsigned short*)alloc((size_t)N * 64 * 2);
    unsigned short* uA   = (unsigned short*)alloc((size_t)N * 64 * 2);
    unsigned short* uB   = (unsigned short*)alloc((size_t)N * 64 * 2);
    float* dinv    = (float*)alloc((size_t)N * 4);
    int*   row_ptr = (int*)alloc((size_t)(N + 1) * 4);
    int*   btot    = (int*)alloc(2048);
    int*   bstart  = (int*)alloc(2048);
    int*   bcur    = (int*)alloc(2048);
    int2*  ebuf    = (int2*)alloc((size_t)E * 8);
    int*   cols    = (int*)alloc((size_t)E * 4);
    short* w1f     = (short*)alloc((size_t)F * 64 * 2);
    short* w2f     = (short*)alloc((size_t)64 * 64 * 2);

    int neb = (E + 4095) / 4096;

    k_zero<<<2, 256, 0, stream>>>(btot, NB);
    k_hist<<<neb, 256, 0, stream>>>(ei, btot, E, NB);
    k_scanb<<<1, 512, 0, stream>>>(btot, bstart, bcur, row_ptr, NB, N, E);
    k_part<<<neb, 256, 0, stream>>>(ei, bcur, ebuf, E, NB);
    k_bucket<<<NB, 256, 0, stream>>>(ebuf, bstart, row_ptr, dinv, cols, N);
    k_pack_w1<<<(F * 64) / 256, 256, 0, stream>>>(w1, w1f);
    k_pack_w2<<<16, 256, 0, stream>>>(w2, w2f);
    k_mlp<<<(N + 63) / 64, 256, 0, stream>>>(x, (const short8*)w1f, b1,
                                             (const short8*)w2f, b2, dinv, ah, u0, N, F);

    const unsigned short* uin = u0;
    unsigned short* bufs[2] = {uA, uB};
    for (int k = 0; k < KSTEPS - 1; ++k) {
        unsigned short* uo = bufs[k & 1];
        k_prop<<<(N + 3) / 4, 256, 0, stream>>>(uin, ah, dinv, row_ptr, cols, uo, N);
        uin = uo;
    }
    k_prop_lsm<<<(N + 3) / 4, 256, 0, stream>>>(uin, ah, dinv, row_ptr, cols, (float*)d_out, N);
}